// Round 5
// baseline (453.798 us; speedup 1.0000x reference)
//
#include <hip/hip_runtime.h>

// 9x9 local-max peak detection (threshold 0.5) on 8192x8192 fp32.
//
// Key identity: threshold t(x)=x*[x>0.5] commutes with max (monotone), so
//   conf[r][c] = (M > 0.5 && M == raw[r][c]) ? M : 0,  M = 9x9 raw max.
// 0-padding == -inf padding: a pad value only wins the max when all <= 0,
// and the >0.5 gate kills that case.
//
// Round-5 structure — LDS-ring streaming with async DMA prefetch:
//   Cross-round evidence (R0-R4): kernel pinned at ~166 us, latency-bound:
//   period 1250 cyc/wave-row vs ~300 VALU + traffic 0.89x ideal; prefetch
//   depth and occupancy BOTH capped by the 64-VGPR wall (R2: 32 regs ->
//   spill disaster). Fix: prefetch depth moves to LDS via
//   __builtin_amdgcn_global_load_lds (no VGPR cost for in-flight rows).
//   Each wave owns a private 9-slot ring of raw rows (268 floats = cols
//   -4..263 of its 256-col band), staged 9 rows ahead (2 DMA insts/row),
//   consumed as 3x ds_read_b128 (l/v/r at +-16B). Wave-private ring -> no
//   barriers. Manual counted vmcnt (16 / 17+k / 25, derived exactly; DMAs
//   are ALWAYS issued per row -- OOB rows clamp the source address and are
//   zeroed at consume time -- so the counts never drift). lgkmcnt(0) after
//   the reads fences the slot's re-DMA against read service.
//   hm/fl rings stay in registers (45 regs persistent, fits 64 cap).

#define W 8192
#define H 8192
#define THRESH 0.5f
#define SR 64           // output rows per wave-strip
#define SLOTS 9         // LDS ring depth in rows
#define RB 268          // floats per LDS row: band cols [-4, 264)
#define WAVES 4

typedef float v4f __attribute__((ext_vector_type(4)));

template <int N>
__device__ __forceinline__ void wait_vm() {
    asm volatile("s_waitcnt vmcnt(%0)" :: "n"(N) : "memory");
}
__device__ __forceinline__ void wait_lgkm0() {
    asm volatile("s_waitcnt lgkmcnt(0)" ::: "memory");
}

__global__ __launch_bounds__(256, 4) void peak_stream(const float* __restrict__ in,
                                                      float* __restrict__ out) {
    __shared__ float smem[WAVES * SLOTS * RB];   // 38,592 B -> 4 blocks/CU
    const int lane  = threadIdx.x;               // 0..63
    const int bcol0 = blockIdx.x * 256;
    const int col0  = bcol0 + lane * 4;          // this lane's 4 output cols
    const int r0    = (blockIdx.y * WAVES + threadIdx.y) * SR;
    const int rlast = r0 + SR + 3;               // last input row this strip needs
    float* const ring = smem + threadIdx.y * (SLOTS * RB);

    // DMA source cols. inst1: 64 lanes cover floats [0,256) = cols -4..251.
    // inst2: lanes 0..2 cover floats [256,268) = cols 252..263.
    const int c1 = bcol0 - 4 + lane * 4;
    const bool m1 = (c1 >= 0);                       // false only lane0 @ bx==0
    const int c2 = bcol0 + 252 + lane * 4;
    const bool a2 = (lane < 3) && (c2 + 4 <= W);     // in-bounds inst2 lanes
    const bool z2 = (lane < 3) && (c2 + 4 > W);      // OOB inst2 lanes @ bx==31

    // Stage input row rp into ring slot. ALWAYS issues exactly 2 DMA insts
    // (vmcnt bookkeeping depends on it): OOB rows clamp the source address
    // (harmless re-read; rows beyond the strip re-read rlast = L1-hot) and
    // are replaced by zeros at consume time. Col-OOB lanes are exec-masked
    // off the DMA and their LDS bytes zeroed with ds_writes (lgkm-tracked).
    auto prefetch = [&](int rp, int slot) {
        int rpc = rp < rlast ? rp : rlast;
        rpc = rpc < 0 ? 0 : (rpc >= H ? H - 1 : rpc);
        const float* row = in + (size_t)rpc * W;
        float* const dst = ring + slot * RB;
        if (m1) __builtin_amdgcn_global_load_lds(row + c1, dst, 16, 0, 0);
        if (a2) __builtin_amdgcn_global_load_lds(row + c2, dst + 256, 16, 0, 0);
        if (!m1) *(v4f*)(dst + 4 * lane) = (v4f){0.f, 0.f, 0.f, 0.f};
        if (z2)  *(v4f*)(dst + 256 + 4 * lane) = (v4f){0.f, 0.f, 0.f, 0.f};
    };

    v4f hm[SLOTS];   // ring: horizontal 9-max of the last 9 input rows
    int fl[SLOTS];   // ring: 4-bit flags, bit j = (hmax.j == raw.j)

    // Consume input row rin from ring slot k (static); emit output rin-4.
    auto consume = [&](int rin, int k, bool emit) {
        v4f l, v, r;
        if ((unsigned)rin < (unsigned)H) {
            const float* rowp = ring + k * RB + 4 * lane;
            l = *(const v4f*)(rowp);        // cols 4i-4..4i-1
            v = *(const v4f*)(rowp + 4);    // cols 4i  ..4i+3 (center)
            r = *(const v4f*)(rowp + 8);    // cols 4i+4..4i+7
        } else {
            l = v = r = (v4f){0.f, 0.f, 0.f, 0.f};
        }
        wait_lgkm0();  // reads serviced before caller re-DMAs this slot
        const float common = fmaxf(fmaxf(fmaxf(l.w, v.x), fmaxf(v.y, v.z)),
                                   fmaxf(v.w, r.x));     // max of middle 6
        const float m12  = fmaxf(l.y, l.z);
        const float m910 = fmaxf(r.y, r.z);
        v4f o;
        o.x = fmaxf(common, fmaxf(l.x, m12));
        o.y = fmaxf(common, fmaxf(m12, r.y));
        o.z = fmaxf(common, fmaxf(l.z, m910));
        o.w = fmaxf(common, fmaxf(m910, r.w));
        hm[k] = o;
        fl[k] = (o.x == v.x ? 1 : 0) | (o.y == v.y ? 2 : 0) |
                (o.z == v.z ? 4 : 0) | (o.w == v.w ? 8 : 0);
        if (emit) {
            v4f m = hm[0];
#pragma unroll
            for (int j = 1; j < 9; ++j) {
                m.x = fmaxf(m.x, hm[j].x);
                m.y = fmaxf(m.y, hm[j].y);
                m.z = fmaxf(m.z, hm[j].z);
                m.w = fmaxf(m.w, hm[j].w);
            }
            const v4f hc = hm[(k + 5) % 9];  // h-max of window-center row
            const int fc = fl[(k + 5) % 9];
            v4f ov;
            ov.x = (m.x > THRESH && m.x == hc.x && (fc & 1)) ? m.x : 0.f;
            ov.y = (m.y > THRESH && m.y == hc.y && (fc & 2)) ? m.y : 0.f;
            ov.z = (m.z > THRESH && m.z == hc.z && (fc & 4)) ? m.z : 0.f;
            ov.w = (m.w > THRESH && m.w == hc.w && (fc & 8)) ? m.w : 0.f;
            const int rout = rin - 4;
            __builtin_nontemporal_store(ov, (v4f*)(out + (size_t)rout * W + col0));
        }
    };

    // Warmup: stage rows r0-4 .. r0+4 into slots 0..8 (9 rows, 18 DMAs).
#pragma unroll
    for (int t = 0; t < 9; ++t) prefetch(r0 - 4 + t, t);

    // Body j: wait for row j's DMA -> consume slot j%9 -> restage slot with
    // row j+9. Ops newer than row j's DMA pair at the wait:
    //   chunk 0 (j=0..8, rows from warmup): 2*(8-j) warmup + 2*j bodies = 16
    //   chunk 1 (j=9..17): 16 DMA + (j-8) stores (emit starts at j=8) = 17+k
    //   steady  (j>=18):   16 DMA + 8 stores + prior-body store = 25
#define C0(K) wait_vm<16>();     consume(r0 - 4 + K, K, K >= 8); prefetch(r0 + 5 + K, K);
#define C1(K) wait_vm<17 + K>(); consume(r0 + 5 + K, K, true);   prefetch(r0 + 14 + K, K);
    C0(0) C0(1) C0(2) C0(3) C0(4) C0(5) C0(6) C0(7) C0(8)
    C1(0) C1(1) C1(2) C1(3) C1(4) C1(5) C1(6) C1(7) C1(8)
#undef C0
#undef C1
    // chunks 2..7: j = 18..71 (rows r0+14 .. r0+67)
    for (int tc = 18; tc < 72; tc += 9) {
#pragma unroll
        for (int k = 0; k < 9; ++k) {
            wait_vm<25>();
            consume(r0 - 4 + tc + k, k, true);
            prefetch(r0 + 5 + tc + k, k);
        }
    }
}

extern "C" void kernel_launch(void* const* d_in, const int* in_sizes, int n_in,
                              void* d_out, int out_size, void* d_ws, size_t ws_size,
                              hipStream_t stream) {
    const float* in = (const float*)d_in[0];
    float* out = (float*)d_out;
    dim3 grid(W / 256, H / (WAVES * SR));   // 32 x 32 = 1024 blocks = 4/CU
    dim3 block(64, WAVES, 1);               // 4 waves; wave ty owns one strip
    peak_stream<<<grid, block, 0, stream>>>(in, out);
}